// Round 20
// baseline (159.593 us; speedup 1.0000x reference)
//
#include <hip/hip_runtime.h>
#include <stdint.h>

typedef __attribute__((ext_vector_type(8))) __bf16 bf16x8;
typedef __attribute__((ext_vector_type(16))) float f32x16;
typedef __attribute__((ext_vector_type(4))) unsigned int u32x4;
typedef __attribute__((ext_vector_type(4))) float f32x4;
typedef __attribute__((ext_vector_type(2))) float f32x2;
typedef unsigned int u32;
typedef unsigned short u16;

#define THETA 0.7f

__host__ __device__ constexpr float pht_val(int q) {
  return (q == 12) ? (-4.0f + 1e-6f)
       : (q == 7 || q == 11 || q == 13 || q == 17) ? (1.0f + 1e-6f)
       : 1e-6f;
}

__device__ __forceinline__ u16 f2bf(float v) {
  u32 u = __builtin_bit_cast(u32, v);
  return (u16)((u + 0x7fffu + ((u >> 16) & 1u)) >> 16);
}

// ---------------- kernel 1: build K_eff, packed as MFMA A-fragments -------
__global__ __launch_bounds__(256) void k_prep(const float* __restrict__ wgt,
                                              const float* __restrict__ alpha,
                                              u16* __restrict__ apack) {
  int t = blockIdx.x * 256 + threadIdx.x;   // 4096 threads: (o, ci)
  int o = t >> 6, ci = t & 63;
  const float* wp = wgt + ((size_t)(o * 64 + ci)) * 25;
  float wv[25], sumw = 0.f;
#pragma unroll
  for (int p = 0; p < 25; ++p) { wv[p] = wp[p]; sumw += wv[p]; }
  float keff[25];
#pragma unroll
  for (int p = 0; p < 25; ++p) keff[p] = pht_val(p) * wv[p];  // a=0 (identity)
  constexpr int TP[33] = {0,1,2,3,4,6,7,9,12,13,  0,1,2,3,4,  0, 0, 0,
                          0,5,10,15,20,  0,5,6,10,11,12,15,17,20,21};
  constexpr int TQ[33] = {5,6,12,17,23,10,16,22,20,21,  0,5,10,15,20,  5, 0, 5,
                          0,6,7,8,9,  5,6,2,12,8,4,17,9,23,14};
#pragma unroll
  for (int e = 0; e < 33; ++e) keff[TP[e]] += pht_val(TQ[e]) * wv[TQ[e]];

  float al = alpha[0];
  int kc = ci >> 4, oh = o >> 5;
  int lane = ((ci >> 3) & 1) * 32 + (o & 31);   // A-frag: lane=(k/8)*32+m
#pragma unroll
  for (int p = 0; p < 25; ++p) {
    float v = al * (keff[p] * 0.125f);
    if (p == 12) v -= THETA * sumw;             // fold 1x1 branch into center
    size_t idx = ((((size_t)p * 4 + kc) * 2 + oh) * 64 + lane) * 8 + (ci & 7);
    apack[idx] = f2bf(v);
  }
}

// ---------------- kernel 2: FUSED conv, wave-private barrier-free ---------
// ZERO s_barrier. Wave = (q32 px-quarter, rp row-pair), owns 2 out rows x
// 32 px x ALL 64 o (4 accs = 64 AGPR). Each wave stages its OWN 6-row x
// 40-col x 16-ch window into a PRIVATE LDS dbuf (producer == consumer ==
// same wave -> lgkmcnt(0) is the only sync; waves drift freely, SIMD's 2
// waves anti-phase). Strides RS=1312 (328w=8 mod 32), SS=656 (164w=4):
// write banks cover all 32, reads = contiguous 512B sweeps.
#define RS 1312
#define SS 656
#define BUFB 7872    // 6*RS
#define WVB 15744    // 2*BUFB
#define PSTEP 262144 // 16 ch * 16384 floats

#define MM(A, B, C) __builtin_amdgcn_mfma_f32_32x32x16_bf16((A), __builtin_bit_cast(bf16x8, (B)), (C), 0, 0, 0)

#define PK2(A_, B_) ({ u32 r_;                                              \
    asm("v_cvt_pk_bf16_f32 %0, %1, %2" : "=v"(r_) : "v"(A_), "v"(B_));      \
    r_; })

#define LDBR(DX, KC) do {                                                   \
    const char* pb_ = rdb + (((KC) & 1) * BUFB) + (DX) * 16;                \
    br0 = *(const u32x4*)(pb_ + 0 * RS);                                    \
    br1 = *(const u32x4*)(pb_ + 1 * RS);                                    \
    br2 = *(const u32x4*)(pb_ + 2 * RS);                                    \
    br3 = *(const u32x4*)(pb_ + 3 * RS);                                    \
    br4 = *(const u32x4*)(pb_ + 4 * RS);                                    \
    br5 = *(const u32x4*)(pb_ + 5 * RS);                                    \
  } while (0)

#define LDAF(DX, KC) do {                                                   \
    af00 = apb[(size_t)((0 * 5 + (DX)) * 512 + (KC) * 128)];                \
    af01 = apb[(size_t)((1 * 5 + (DX)) * 512 + (KC) * 128)];                \
    af02 = apb[(size_t)((2 * 5 + (DX)) * 512 + (KC) * 128)];                \
    af03 = apb[(size_t)((3 * 5 + (DX)) * 512 + (KC) * 128)];                \
    af04 = apb[(size_t)((4 * 5 + (DX)) * 512 + (KC) * 128)];                \
    af10 = apb[(size_t)((0 * 5 + (DX)) * 512 + (KC) * 128 + 64)];           \
    af11 = apb[(size_t)((1 * 5 + (DX)) * 512 + (KC) * 128 + 64)];           \
    af12 = apb[(size_t)((2 * 5 + (DX)) * 512 + (KC) * 128 + 64)];           \
    af13 = apb[(size_t)((3 * 5 + (DX)) * 512 + (KC) * 128 + 64)];           \
    af14 = apb[(size_t)((4 * 5 + (DX)) * 512 + (KC) * 128 + 64)];           \
  } while (0)

// a{r}{oh}: r = out row (0,1), oh = o-half. j = r + dy.
#define BURST() do {                                                        \
    bf16x8 A_;                                                              \
    A_ = __builtin_bit_cast(bf16x8, af00);                                  \
    a00 = MM(A_, br0, a00); a10 = MM(A_, br1, a10);                         \
    A_ = __builtin_bit_cast(bf16x8, af10);                                  \
    a01 = MM(A_, br0, a01); a11 = MM(A_, br1, a11);                         \
    A_ = __builtin_bit_cast(bf16x8, af01);                                  \
    a00 = MM(A_, br1, a00); a10 = MM(A_, br2, a10);                         \
    A_ = __builtin_bit_cast(bf16x8, af11);                                  \
    a01 = MM(A_, br1, a01); a11 = MM(A_, br2, a11);                         \
    A_ = __builtin_bit_cast(bf16x8, af02);                                  \
    a00 = MM(A_, br2, a00); a10 = MM(A_, br3, a10);                         \
    A_ = __builtin_bit_cast(bf16x8, af12);                                  \
    a01 = MM(A_, br2, a01); a11 = MM(A_, br3, a11);                         \
    A_ = __builtin_bit_cast(bf16x8, af03);                                  \
    a00 = MM(A_, br3, a00); a10 = MM(A_, br4, a10);                         \
    A_ = __builtin_bit_cast(bf16x8, af13);                                  \
    a01 = MM(A_, br3, a01); a11 = MM(A_, br4, a11);                         \
    A_ = __builtin_bit_cast(bf16x8, af04);                                  \
    a00 = MM(A_, br4, a00); a10 = MM(A_, br5, a10);                         \
    A_ = __builtin_bit_cast(bf16x8, af14);                                  \
    a01 = MM(A_, br4, a01); a11 = MM(A_, br5, a11);                         \
  } while (0)

#define DXI(DX, KC) do { LDBR(DX, KC); LDAF(DX, KC); BURST(); } while (0)

// slot A (all lanes): j=l>>4 (0..3), subg=(l>>3)&1, qi=l&7
#define SLOADA(P) do {                                                      \
    if (okA) {                                                              \
      const float* p_ = pA + (size_t)(P) * PSTEP;                           \
      smA0 = *(const f32x4*)(p_);              smA1 = *(const f32x4*)(p_ + 16384);      \
      smA2 = *(const f32x4*)(p_ + 2 * 16384);  smA3 = *(const f32x4*)(p_ + 3 * 16384);  \
      smA4 = *(const f32x4*)(p_ + 4 * 16384);  smA5 = *(const f32x4*)(p_ + 5 * 16384);  \
      smA6 = *(const f32x4*)(p_ + 6 * 16384);  smA7 = *(const f32x4*)(p_ + 7 * 16384);  \
    } else {                                                                \
      smA0 = 0; smA1 = 0; smA2 = 0; smA3 = 0;                               \
      smA4 = 0; smA5 = 0; smA6 = 0; smA7 = 0;                               \
    }                                                                       \
  } while (0)

#define SWRITEA(P) do {                                                     \
    char* w_ = wA + (((P) & 1) * BUFB);                                     \
    u32x4 t_;                                                               \
    t_[0] = PK2(smA0.x, smA1.x); t_[1] = PK2(smA2.x, smA3.x);               \
    t_[2] = PK2(smA4.x, smA5.x); t_[3] = PK2(smA6.x, smA7.x);               \
    *(u32x4*)(w_ + 0)  = t_;                                                \
    t_[0] = PK2(smA0.y, smA1.y); t_[1] = PK2(smA2.y, smA3.y);               \
    t_[2] = PK2(smA4.y, smA5.y); t_[3] = PK2(smA6.y, smA7.y);               \
    *(u32x4*)(w_ + 16) = t_;                                                \
    t_[0] = PK2(smA0.z, smA1.z); t_[1] = PK2(smA2.z, smA3.z);               \
    t_[2] = PK2(smA4.z, smA5.z); t_[3] = PK2(smA6.z, smA7.z);               \
    *(u32x4*)(w_ + 32) = t_;                                                \
    t_[0] = PK2(smA0.w, smA1.w); t_[1] = PK2(smA2.w, smA3.w);               \
    t_[2] = PK2(smA4.w, smA5.w); t_[3] = PK2(smA6.w, smA7.w);               \
    *(u32x4*)(w_ + 48) = t_;                                                \
  } while (0)

// slot B (lanes 0..31): s=64+l -> j=4+(l>>4), subg=(l>>3)&1, qi=l&7
#define SLOADB(P) do {                                                      \
    if (okB) {                                                              \
      const float* p_ = pB + (size_t)(P) * PSTEP;                           \
      smA0 = *(const f32x4*)(p_);              smA1 = *(const f32x4*)(p_ + 16384);      \
      smA2 = *(const f32x4*)(p_ + 2 * 16384);  smA3 = *(const f32x4*)(p_ + 3 * 16384);  \
      smA4 = *(const f32x4*)(p_ + 4 * 16384);  smA5 = *(const f32x4*)(p_ + 5 * 16384);  \
      smA6 = *(const f32x4*)(p_ + 6 * 16384);  smA7 = *(const f32x4*)(p_ + 7 * 16384);  \
    } else {                                                                \
      smA0 = 0; smA1 = 0; smA2 = 0; smA3 = 0;                               \
      smA4 = 0; smA5 = 0; smA6 = 0; smA7 = 0;                               \
    }                                                                       \
  } while (0)

#define SWRITEB(P) do {                                                     \
    if (mB) {                                                               \
      char* w_ = wB + (((P) & 1) * BUFB);                                   \
      u32x4 t_;                                                             \
      t_[0] = PK2(smA0.x, smA1.x); t_[1] = PK2(smA2.x, smA3.x);             \
      t_[2] = PK2(smA4.x, smA5.x); t_[3] = PK2(smA6.x, smA7.x);             \
      *(u32x4*)(w_ + 0)  = t_;                                              \
      t_[0] = PK2(smA0.y, smA1.y); t_[1] = PK2(smA2.y, smA3.y);             \
      t_[2] = PK2(smA4.y, smA5.y); t_[3] = PK2(smA6.y, smA7.y);             \
      *(u32x4*)(w_ + 16) = t_;                                              \
      t_[0] = PK2(smA0.z, smA1.z); t_[1] = PK2(smA2.z, smA3.z);             \
      t_[2] = PK2(smA4.z, smA5.z); t_[3] = PK2(smA6.z, smA7.z);             \
      *(u32x4*)(w_ + 32) = t_;                                              \
      t_[0] = PK2(smA0.w, smA1.w); t_[1] = PK2(smA2.w, smA3.w);             \
      t_[2] = PK2(smA4.w, smA5.w); t_[3] = PK2(smA6.w, smA7.w);             \
      *(u32x4*)(w_ + 48) = t_;                                              \
    }                                                                       \
  } while (0)

// halo (lanes 0..23): j=l>>2, subg=(l>>1)&1, side=l&1; 2 px x 8 ch
#define SLOADH(P) do {                                                      \
    if (okH) {                                                              \
      const float* p_ = pH + (size_t)(P) * PSTEP;                           \
      shH0 = *(const f32x2*)(p_);              shH1 = *(const f32x2*)(p_ + 16384);      \
      shH2 = *(const f32x2*)(p_ + 2 * 16384);  shH3 = *(const f32x2*)(p_ + 3 * 16384);  \
      shH4 = *(const f32x2*)(p_ + 4 * 16384);  shH5 = *(const f32x2*)(p_ + 5 * 16384);  \
      shH6 = *(const f32x2*)(p_ + 6 * 16384);  shH7 = *(const f32x2*)(p_ + 7 * 16384);  \
    } else {                                                                \
      shH0 = 0; shH1 = 0; shH2 = 0; shH3 = 0;                               \
      shH4 = 0; shH5 = 0; shH6 = 0; shH7 = 0;                               \
    }                                                                       \
  } while (0)

#define SWRITEH(P) do {                                                     \
    if (mH) {                                                               \
      char* w_ = wH + (((P) & 1) * BUFB);                                   \
      u32x4 t_;                                                             \
      t_[0] = PK2(shH0.x, shH1.x); t_[1] = PK2(shH2.x, shH3.x);             \
      t_[2] = PK2(shH4.x, shH5.x); t_[3] = PK2(shH6.x, shH7.x);             \
      *(u32x4*)(w_ + 0)  = t_;                                              \
      t_[0] = PK2(shH0.y, shH1.y); t_[1] = PK2(shH2.y, shH3.y);             \
      t_[2] = PK2(shH4.y, shH5.y); t_[3] = PK2(shH6.y, shH7.y);             \
      *(u32x4*)(w_ + 16) = t_;                                              \
    }                                                                       \
  } while (0)

#define SBAR0() __builtin_amdgcn_sched_barrier(0)

// one phase: compute kc=KC from buf[KC&1], stage group P=KC+1 into buf[P&1]
#define CPHASE(P, KC) do {                                                  \
    SLOADA(P);                                                              \
    DXI(0, KC);                                                             \
    DXI(1, KC);                                                             \
    SWRITEA(P); SBAR0();                                                    \
    SLOADB(P);                                                              \
    DXI(2, KC);                                                             \
    SWRITEB(P); SBAR0();                                                    \
    SLOADH(P);                                                              \
    DXI(3, KC);                                                             \
    SWRITEH(P);                                                             \
    DXI(4, KC);                                                             \
    asm volatile("s_waitcnt lgkmcnt(0)" ::: "memory");                      \
    SBAR0();                                                                \
  } while (0)

__global__ __launch_bounds__(256, 2) void k_conv(const float* __restrict__ x,
                                                 const u32x4* __restrict__ apv,
                                                 float* __restrict__ out) {
  __shared__ char tile[4 * WVB];              // 62976 B -> 2 blocks/CU
  int bid = blockIdx.x;
  int lg = (bid & 7) * 256 + (bid >> 3);      // XCD swizzle (2048%8==0)
  int ph = lg & 1, yt = (lg >> 1) & 31, n = lg >> 6;
  int y0 = yt * 4, px0 = ph * 64;
  int tid = threadIdx.x;
  int l = tid & 63, wv = tid >> 6;
  int q32 = wv >> 1, rp = wv & 1;
  int pxq = px0 + q32 * 32;
  int yA = y0 + 2 * rp;                       // wave's 2 output rows
  int l31 = l & 31, lhi = l >> 5;

  const float* xn = x + (size_t)n * (64 * 16384);
  char* wbase = tile + wv * WVB;

  // slot A decode (all shifts)
  int jA = l >> 4, sgA = (l >> 3) & 1, qiA = l & 7;
  int syA = yA - 2 + jA;
  bool okA = (unsigned)syA < 128u;
  const float* pA = xn + (size_t)(8 * sgA) * 16384
                    + (size_t)(okA ? syA : 0) * 128 + pxq + 4 * qiA;
  char* wA = wbase + jA * RS + sgA * SS + (4 + 4 * qiA) * 16;
  // slot B (lanes < 32)
  bool mB = l < 32;
  int jB = 4 + (l >> 4), sgB = (l >> 3) & 1, qiB = l & 7;
  int syB = yA - 2 + jB;
  bool okB = mB && (unsigned)syB < 128u;
  const float* pB = xn + (size_t)(8 * sgB) * 16384
                    + (size_t)(okB ? syB : 0) * 128 + pxq + 4 * qiB;
  char* wB = wbase + (mB ? jB : 0) * RS + sgB * SS + (4 + 4 * qiB) * 16;
  // halo (lanes < 24)
  bool mH = l < 24;
  int jH = l >> 2, sgH = (l >> 1) & 1, sdH = l & 1;
  int syH = yA - 2 + jH;
  int pxH = sdH ? pxq + 32 : pxq - 2;
  bool okH = mH && ((unsigned)syH < 128u) && ((unsigned)pxH < 127u);
  const float* pH = xn + (size_t)(8 * sgH) * 16384
                    + (size_t)(okH ? syH : 0) * 128 + (okH ? pxH : 0);
  char* wH = wbase + (mH ? jH : 0) * RS + sgH * SS + (sdH ? 36 : 2) * 16;

  // compute mapping
  const u32x4* apb = apv + l;                 // oh0 at +0, oh1 at +64
  const char* rdb = wbase + lhi * SS + (l31 + 2) * 16;

  f32x4 smA0, smA1, smA2, smA3, smA4, smA5, smA6, smA7;
  f32x2 shH0, shH1, shH2, shH3, shH4, shH5, shH6, shH7;
  u32x4 br0, br1, br2, br3, br4, br5;
  u32x4 af00, af01, af02, af03, af04, af10, af11, af12, af13, af14;
  f32x16 a00 = 0, a01 = 0, a10 = 0, a11 = 0;  // a{row}{oh}

  // prologue: stage group 0 into buf0 (own-wave only; no barrier anywhere)
  SLOADA(0); SWRITEA(0); SBAR0();
  SLOADB(0); SWRITEB(0); SBAR0();
  SLOADH(0); SWRITEH(0);
  asm volatile("s_waitcnt lgkmcnt(0)" ::: "memory");
  SBAR0();

  CPHASE(1, 0);
  CPHASE(2, 1);
  CPHASE(3, 2);
  // final phase: compute kc=3 from buf1, no stage
  DXI(0, 3);
  DXI(1, 3);
  DXI(2, 3);
  DXI(3, 3);
  DXI(4, 3);

  // epilogue: C/D layout col=lane&31, row=(rg&3)+8*(rg>>2)+4*(lane>>5)
  float* ob = out + ((size_t)(n * 64) * 128 + yA) * 128 + pxq + l31;
#pragma unroll
  for (int rg = 0; rg < 16; ++rg) {
    int rowc = (rg & 3) + 8 * (rg >> 2) + 4 * lhi;
    float* o0 = ob + (size_t)rowc * 16384;            // oh=0
    float* o1 = o0 + (size_t)32 * 16384;              // oh=1
    o0[0]   = a00[rg];
    o0[128] = a10[rg];
    o1[0]   = a01[rg];
    o1[128] = a11[rg];
  }
}

extern "C" void kernel_launch(void* const* d_in, const int* in_sizes, int n_in,
                              void* d_out, int out_size, void* d_ws, size_t ws_size,
                              hipStream_t stream) {
  const float* x     = (const float*)d_in[0];   // (32,64,128,128) fp32
  const float* wgt   = (const float*)d_in[1];   // (64,64,5,5) fp32
  const float* alpha = (const float*)d_in[2];   // (1,) fp32
  float* out = (float*)d_out;

  u16* apack = (u16*)d_ws;                      // 204800 B

  k_prep<<<16,   256, 0, stream>>>(wgt, alpha, apack);
  k_conv<<<2048, 256, 0, stream>>>(x, (const u32x4*)apack, out);
}

// Round 21
// 112.863 us; speedup vs baseline: 1.4140x; 1.4140x over previous
//
#include <hip/hip_runtime.h>
#include <stdint.h>

typedef __attribute__((ext_vector_type(8))) __bf16 bf16x8;
typedef __attribute__((ext_vector_type(16))) float f32x16;
typedef __attribute__((ext_vector_type(4))) unsigned int u32x4;
typedef __attribute__((ext_vector_type(4))) float f32x4;
typedef __attribute__((ext_vector_type(2))) float f32x2;
typedef unsigned int u32;
typedef unsigned short u16;

#define THETA 0.7f

__host__ __device__ constexpr float pht_val(int q) {
  return (q == 12) ? (-4.0f + 1e-6f)
       : (q == 7 || q == 11 || q == 13 || q == 17) ? (1.0f + 1e-6f)
       : 1e-6f;
}

__device__ __forceinline__ u16 f2bf(float v) {
  u32 u = __builtin_bit_cast(u32, v);
  return (u16)((u + 0x7fffu + ((u >> 16) & 1u)) >> 16);
}

// ---------------- kernel 1: build K_eff, packed as MFMA A-fragments -------
__global__ __launch_bounds__(256) void k_prep(const float* __restrict__ wgt,
                                              const float* __restrict__ alpha,
                                              u16* __restrict__ apack) {
  int t = blockIdx.x * 256 + threadIdx.x;   // 4096 threads: (o, ci)
  int o = t >> 6, ci = t & 63;
  const float* wp = wgt + ((size_t)(o * 64 + ci)) * 25;
  float wv[25], sumw = 0.f;
#pragma unroll
  for (int p = 0; p < 25; ++p) { wv[p] = wp[p]; sumw += wv[p]; }
  float keff[25];
#pragma unroll
  for (int p = 0; p < 25; ++p) keff[p] = pht_val(p) * wv[p];  // a=0 (identity)
  constexpr int TP[33] = {0,1,2,3,4,6,7,9,12,13,  0,1,2,3,4,  0, 0, 0,
                          0,5,10,15,20,  0,5,6,10,11,12,15,17,20,21};
  constexpr int TQ[33] = {5,6,12,17,23,10,16,22,20,21,  0,5,10,15,20,  5, 0, 5,
                          0,6,7,8,9,  5,6,2,12,8,4,17,9,23,14};
#pragma unroll
  for (int e = 0; e < 33; ++e) keff[TP[e]] += pht_val(TQ[e]) * wv[TQ[e]];

  float al = alpha[0];
  int kc = ci >> 4, oh = o >> 5;
  int lane = ((ci >> 3) & 1) * 32 + (o & 31);   // A-frag: lane=(k/8)*32+m
#pragma unroll
  for (int p = 0; p < 25; ++p) {
    float v = al * (keff[p] * 0.125f);
    if (p == 12) v -= THETA * sumw;             // fold 1x1 branch into center
    size_t idx = ((((size_t)p * 4 + kc) * 2 + oh) * 64 + lane) * 8 + (ci & 7);
    apack[idx] = f2bf(v);
  }
}

// ---------------- kernel 2: FUSED conv, ch-group double-buffer ------------
// Best-measured configuration (R17, 113.1 us): phase pipeline (stage ch-
// group p while computing kc=p-1), per-channel-group LDS double buffer
// (37.4 KB, conflict-free padded strides GSTR=1168/RSTR=2336), SGB-pinned
// 19-ITER compute core, lgkm-only raw barrier per phase, (256,2) bound
// (112 VGPR + 64 AGPR -> 2 waves/SIMD; register-quantum confirmed).
#define GSTR 1168
#define RSTR 2336
#define BUFSZ 18688

#define MM(A, B, C) __builtin_amdgcn_mfma_f32_32x32x16_bf16((A), __builtin_bit_cast(bf16x8, (B)), (C), 0, 0, 0)

#define PK2(A_, B_) ({ u32 r_;                                              \
    asm("v_cvt_pk_bf16_f32 %0, %1, %2" : "=v"(r_) : "v"(A_), "v"(B_));      \
    r_; })

#define LDBR(S, DX, KC) do {                                                \
    const char* pb_ = tile + (((KC) & 1) * BUFSZ) + cb0 + (DX) * 16;        \
    br##S##0 = *(const u32x4*)(pb_ + 0 * RSTR);                             \
    br##S##1 = *(const u32x4*)(pb_ + 1 * RSTR);                             \
    br##S##2 = *(const u32x4*)(pb_ + 2 * RSTR);                             \
    br##S##3 = *(const u32x4*)(pb_ + 3 * RSTR);                             \
    br##S##4 = *(const u32x4*)(pb_ + 4 * RSTR);                             \
    br##S##5 = *(const u32x4*)(pb_ + 5 * RSTR);                             \
    br##S##6 = *(const u32x4*)(pb_ + 6 * RSTR);                             \
    br##S##7 = *(const u32x4*)(pb_ + 7 * RSTR);                             \
  } while (0)

#define LDAF(S, DX, KC) do {                                                \
    af##S##0 = apb[(size_t)((0 * 5 + (DX)) * 512 + (KC) * 128)];            \
    af##S##1 = apb[(size_t)((1 * 5 + (DX)) * 512 + (KC) * 128)];            \
    af##S##2 = apb[(size_t)((2 * 5 + (DX)) * 512 + (KC) * 128)];            \
    af##S##3 = apb[(size_t)((3 * 5 + (DX)) * 512 + (KC) * 128)];            \
    af##S##4 = apb[(size_t)((4 * 5 + (DX)) * 512 + (KC) * 128)];            \
  } while (0)

#define BURST(S) do {                                                       \
    bf16x8 A_;                                                              \
    A_ = __builtin_bit_cast(bf16x8, af##S##0);                              \
    a0 = MM(A_, br##S##0, a0); a1 = MM(A_, br##S##1, a1);                   \
    a2 = MM(A_, br##S##2, a2); a3 = MM(A_, br##S##3, a3);                   \
    A_ = __builtin_bit_cast(bf16x8, af##S##1);                              \
    a0 = MM(A_, br##S##1, a0); a1 = MM(A_, br##S##2, a1);                   \
    a2 = MM(A_, br##S##3, a2); a3 = MM(A_, br##S##4, a3);                   \
    A_ = __builtin_bit_cast(bf16x8, af##S##2);                              \
    a0 = MM(A_, br##S##2, a0); a1 = MM(A_, br##S##3, a1);                   \
    a2 = MM(A_, br##S##4, a2); a3 = MM(A_, br##S##5, a3);                   \
    A_ = __builtin_bit_cast(bf16x8, af##S##3);                              \
    a0 = MM(A_, br##S##3, a0); a1 = MM(A_, br##S##4, a1);                   \
    a2 = MM(A_, br##S##5, a2); a3 = MM(A_, br##S##6, a3);                   \
    A_ = __builtin_bit_cast(bf16x8, af##S##4);                              \
    a0 = MM(A_, br##S##4, a0); a1 = MM(A_, br##S##5, a1);                   \
    a2 = MM(A_, br##S##6, a2); a3 = MM(A_, br##S##7, a3);                   \
  } while (0)

#define SGB __builtin_amdgcn_sched_group_barrier
#define SCHED_FULL() do {                                                   \
    SGB(0x020, 5, 0);                                                       \
    SGB(0x100, 2, 0); SGB(0x008, 5, 0);                                     \
    SGB(0x100, 2, 0); SGB(0x008, 5, 0);                                     \
    SGB(0x100, 2, 0); SGB(0x008, 5, 0);                                     \
    SGB(0x100, 2, 0); SGB(0x008, 5, 0);                                     \
  } while (0)

#define ITER(CUR, NXT, DXN, KCN) do {                                       \
    LDBR(NXT, DXN, KCN); LDAF(NXT, DXN, KCN); BURST(CUR); SCHED_FULL();     \
  } while (0)

#define TBAR() do {                                                         \
    asm volatile("s_waitcnt lgkmcnt(0)" ::: "memory");                      \
    __builtin_amdgcn_sched_barrier(0);                                      \
    __builtin_amdgcn_s_barrier();                                           \
    __builtin_amdgcn_sched_barrier(0);                                      \
  } while (0)

// stage loads for ch-group P (sub-granule gp): thread = (rr, quad, gp)
#define SLOADP(P) do {                                                      \
    if (rowok) {                                                            \
      const float* pm_ = xrow + (size_t)(16 * (P) + 8 * gp) * 16384 + pxm;  \
      sm0 = *(const f32x4*)(pm_);              sm1 = *(const f32x4*)(pm_ + 16384);      \
      sm2 = *(const f32x4*)(pm_ + 2 * 16384);  sm3 = *(const f32x4*)(pm_ + 3 * 16384);  \
      sm4 = *(const f32x4*)(pm_ + 4 * 16384);  sm5 = *(const f32x4*)(pm_ + 5 * 16384);  \
      sm6 = *(const f32x4*)(pm_ + 6 * 16384);  sm7 = *(const f32x4*)(pm_ + 7 * 16384);  \
    } else {                                                                \
      sm0 = 0; sm1 = 0; sm2 = 0; sm3 = 0; sm4 = 0; sm5 = 0; sm6 = 0; sm7 = 0; \
    }                                                                       \
    if (hdut) {                                                             \
      if (hok) {                                                            \
        const float* ph_ = xn + (size_t)hsy * 128                           \
                           + (size_t)(16 * (P) + 8 * hgp) * 16384 + hpx;    \
        sh0 = *(const f32x2*)(ph_);              sh1 = *(const f32x2*)(ph_ + 16384);     \
        sh2 = *(const f32x2*)(ph_ + 2 * 16384);  sh3 = *(const f32x2*)(ph_ + 3 * 16384); \
        sh4 = *(const f32x2*)(ph_ + 4 * 16384);  sh5 = *(const f32x2*)(ph_ + 5 * 16384); \
        sh6 = *(const f32x2*)(ph_ + 6 * 16384);  sh7 = *(const f32x2*)(ph_ + 7 * 16384); \
      } else {                                                              \
        sh0 = 0; sh1 = 0; sh2 = 0; sh3 = 0; sh4 = 0; sh5 = 0; sh6 = 0; sh7 = 0; \
      }                                                                     \
    }                                                                       \
  } while (0)

// stage writes for ch-group P (4 main cols + 2 halo cols) into buf[P&1]
#define SWRITEP(P) do {                                                     \
    char* wb_ = tile + (((P) & 1) * BUFSZ) + rr * RSTR + gp * GSTR;         \
    u32x4 w_;                                                               \
    w_[0] = PK2(sm0.x, sm1.x); w_[1] = PK2(sm2.x, sm3.x);                   \
    w_[2] = PK2(sm4.x, sm5.x); w_[3] = PK2(sm6.x, sm7.x);                   \
    *(u32x4*)(wb_ + (cbm + 0) * 16) = w_;                                   \
    w_[0] = PK2(sm0.y, sm1.y); w_[1] = PK2(sm2.y, sm3.y);                   \
    w_[2] = PK2(sm4.y, sm5.y); w_[3] = PK2(sm6.y, sm7.y);                   \
    *(u32x4*)(wb_ + (cbm + 1) * 16) = w_;                                   \
    w_[0] = PK2(sm0.z, sm1.z); w_[1] = PK2(sm2.z, sm3.z);                   \
    w_[2] = PK2(sm4.z, sm5.z); w_[3] = PK2(sm6.z, sm7.z);                   \
    *(u32x4*)(wb_ + (cbm + 2) * 16) = w_;                                   \
    w_[0] = PK2(sm0.w, sm1.w); w_[1] = PK2(sm2.w, sm3.w);                   \
    w_[2] = PK2(sm4.w, sm5.w); w_[3] = PK2(sm6.w, sm7.w);                   \
    *(u32x4*)(wb_ + (cbm + 3) * 16) = w_;                                   \
    if (hdut) {                                                             \
      char* hb_ = tile + (((P) & 1) * BUFSZ) + hrr * RSTR + hgp * GSTR;     \
      u32x4 u_;                                                             \
      u_[0] = PK2(sh0.x, sh1.x); u_[1] = PK2(sh2.x, sh3.x);                 \
      u_[2] = PK2(sh4.x, sh5.x); u_[3] = PK2(sh6.x, sh7.x);                 \
      *(u32x4*)(hb_ + (hc + 0) * 16) = u_;                                  \
      u_[0] = PK2(sh0.y, sh1.y); u_[1] = PK2(sh2.y, sh3.y);                 \
      u_[2] = PK2(sh4.y, sh5.y); u_[3] = PK2(sh6.y, sh7.y);                 \
      *(u32x4*)(hb_ + (hc + 1) * 16) = u_;                                  \
    }                                                                       \
  } while (0)

// one pipelined phase: stage ch-group SP while computing kc=CP
#define CPHASE(SP, CP) do {                                                 \
    SLOADP(SP);                                                             \
    LDBR(A, 0, CP); LDAF(A, 0, CP);                                         \
    ITER(A, B, 1, CP);                                                      \
    ITER(B, A, 2, CP);                                                      \
    SWRITEP(SP);                                                            \
    ITER(A, B, 3, CP);                                                      \
    ITER(B, A, 4, CP);                                                      \
    BURST(A);                                                               \
    TBAR();                                                                 \
  } while (0)

__global__ __launch_bounds__(256, 2) void k_conv(const float* __restrict__ x,
                                                 const u32x4* __restrict__ apv,
                                                 float* __restrict__ out) {
  __shared__ char tile[2 * BUFSZ];            // 37376 B
  int bid = blockIdx.x;
  int lg = (bid & 7) * 256 + (bid >> 3);      // XCD swizzle (2048%8==0)
  int ph = lg & 1, yt = (lg >> 1) & 31, n = lg >> 6;
  int y0 = yt * 4, px0 = ph * 64;
  int tid = threadIdx.x;
  int l = tid & 63;

  // ---- stage thread mapping: (row rr, quad qq, granule parity gp) ----
  const float* xn = x + (size_t)n * (64 * 16384);
  int rr = tid >> 5, qq = (tid >> 1) & 15, gp = tid & 1;
  int sy = y0 + rr - 2;
  bool rowok = (unsigned)sy < 128u;
  const float* xrow = xn + (size_t)(rowok ? sy : 0) * 128;
  int pxm = px0 + 4 * qq;
  int cbm = 4 + 4 * qq;                       // tile col (px = px0+c-4)
  bool hdut = tid < 32;                       // halo: (hrr, side, hgp)
  int hrr = tid >> 2, hside = (tid >> 1) & 1, hgp = tid & 1;
  int hpx = hside ? px0 + 64 : px0 - 2;
  int hc = hside ? 68 : 2;
  int hsy = y0 + hrr - 2;
  bool hok = ((unsigned)hpx < 127u) && ((unsigned)hsy < 128u);
  if (!hok) hsy = 0; if (hpx < 0) hpx = 0;

  // ---- compute mapping ----
  int wv = tid >> 6;
  int oh = wv >> 1, q32 = wv & 1;
  int l31 = l & 31, lhi = l >> 5;
  const u32x4* apb = apv + (size_t)(oh * 64 + l);
  int cb0 = lhi * GSTR + (q32 * 32 + l31 + 2) * 16;

  f32x4 sm0, sm1, sm2, sm3, sm4, sm5, sm6, sm7;
  f32x2 sh0, sh1, sh2, sh3, sh4, sh5, sh6, sh7;
  u32x4 brA0, brA1, brA2, brA3, brA4, brA5, brA6, brA7;
  u32x4 brB0, brB1, brB2, brB3, brB4, brB5, brB6, brB7;
  u32x4 afA0, afA1, afA2, afA3, afA4;
  u32x4 afB0, afB1, afB2, afB3, afB4;
  f32x16 a0 = 0, a1 = 0, a2 = 0, a3 = 0;

  // phase 0: stage ch-group 0 -> buf0
  SLOADP(0);
  SWRITEP(0);
  TBAR();
  // phases 1..3: stage ch-group p -> buf[p&1], compute kc=p-1 from buf[(p-1)&1]
  CPHASE(1, 0);
  CPHASE(2, 1);
  CPHASE(3, 2);
  // phase 4: compute kc=3 from buf1 (no stage, no barrier)
  LDBR(A, 0, 3); LDAF(A, 0, 3);
  ITER(A, B, 1, 3);
  ITER(B, A, 2, 3);
  ITER(A, B, 3, 3);
  ITER(B, A, 4, 3);
  BURST(A);

  // ---- epilogue: C/D layout col=lane&31, row=(rg&3)+8*(rg>>2)+4*(lane>>5)
  float* ob = out + ((size_t)(n * 64 + oh * 32) * 128 + y0) * 128
              + px0 + q32 * 32 + l31;
#pragma unroll
  for (int rg = 0; rg < 16; ++rg) {
    int orow = (rg & 3) + 8 * (rg >> 2) + 4 * lhi;
    float* obr = ob + (size_t)orow * 16384;
    obr[0]   = a0[rg];
    obr[128] = a1[rg];
    obr[256] = a2[rg];
    obr[384] = a3[rg];
  }
}

extern "C" void kernel_launch(void* const* d_in, const int* in_sizes, int n_in,
                              void* d_out, int out_size, void* d_ws, size_t ws_size,
                              hipStream_t stream) {
  const float* x     = (const float*)d_in[0];   // (32,64,128,128) fp32
  const float* wgt   = (const float*)d_in[1];   // (64,64,5,5) fp32
  const float* alpha = (const float*)d_in[2];   // (1,) fp32
  float* out = (float*)d_out;

  u16* apack = (u16*)d_ws;                      // 204800 B

  k_prep<<<16,   256, 0, stream>>>(wgt, alpha, apack);
  k_conv<<<2048, 256, 0, stream>>>(x, (const u32x4*)apack, out);
}